// Round 8
// baseline (325.773 us; speedup 1.0000x reference)
//
#include <hip/hip_runtime.h>

// ---------------------------------------------------------------------------
// MultiHeadAttention: B=2, S=2048, D=1024, H=16, hd=64
// Interleaved head split: Q[b,h,s,d] = proj[b,s, d*16+h]; scale = 1/32.
// Precision: split-bf16 (hi+lo) emulated-fp32 for Q/K path. V/attn/out plain bf16.
// v7 flash: 128-row q-tiles (2 M-frags/wave) -> each K/V LDS read feeds 2x
// MFMA work; LDS traffic per unit work ~1.8x lower (it was the binding pipe:
// v6 showed extra occupancy is neutral -> throughput-bound, not latency).
// Grid 512 (2 blocks/CU), longest-first, XCD-pinned heads. Merged layouts,
// fused QKV GEMM, permuted-weight out-proj unchanged from v5/v6.
// ---------------------------------------------------------------------------

typedef __bf16 bf16x8 __attribute__((ext_vector_type(8)));
typedef float  f32x4  __attribute__((ext_vector_type(4)));

#define S_LEN  2048
#define DMODEL 1024
#define NHEADS 16
#define HDIM   64
#define LOG2E  1.44269504088896340736f

__device__ __forceinline__ void gll16(const __bf16* g, __bf16* l) {
    __builtin_amdgcn_global_load_lds(
        (const __attribute__((address_space(1))) unsigned int*)g,
        (__attribute__((address_space(3))) unsigned int*)l, 16, 0, 0);
}

// ---------------------------------------------------------------------------
// f32 -> (hi, lo) bf16 split, vectorized
// ---------------------------------------------------------------------------
__global__ __launch_bounds__(256) void conv_split(const float* __restrict__ x,
                                                  __bf16* __restrict__ hi,
                                                  __bf16* __restrict__ lo, int n4) {
    int i = blockIdx.x * 256 + threadIdx.x;
    if (i >= n4) return;
    float4 v = ((const float4*)x)[i];
    __bf16 h0 = (__bf16)v.x, h1 = (__bf16)v.y, h2 = (__bf16)v.z, h3 = (__bf16)v.w;
    ushort4 hh, ll;
    hh.x = __builtin_bit_cast(unsigned short, h0);
    hh.y = __builtin_bit_cast(unsigned short, h1);
    hh.z = __builtin_bit_cast(unsigned short, h2);
    hh.w = __builtin_bit_cast(unsigned short, h3);
    ll.x = __builtin_bit_cast(unsigned short, (__bf16)(v.x - (float)h0));
    ll.y = __builtin_bit_cast(unsigned short, (__bf16)(v.y - (float)h1));
    ll.z = __builtin_bit_cast(unsigned short, (__bf16)(v.z - (float)h2));
    ll.w = __builtin_bit_cast(unsigned short, (__bf16)(v.w - (float)h3));
    ((ushort4*)hi)[i] = hh;
    ((ushort4*)lo)[i] = ll;
}

// ---------------------------------------------------------------------------
// Fused weight transposes. z=0: qw -> split, col-permuted (row c=perm(n)).
// z=1: kw likewise. z=2: vw plain wt[n][k]. z=3: ow plain, k-permuted
// (owt[n][perm(k)]), matching attnb's merged channel c=h*64+d.
// perm(i) = (i&15)*64 + (i>>4).
// ---------------------------------------------------------------------------
__global__ __launch_bounds__(256) void transpose_all(
    const float* __restrict__ qw, const float* __restrict__ kw,
    const float* __restrict__ vw, const float* __restrict__ ow,
    __bf16* __restrict__ qwthi, __bf16* __restrict__ qwtlo,
    __bf16* __restrict__ kwthi, __bf16* __restrict__ kwtlo,
    __bf16* __restrict__ vwt,  __bf16* __restrict__ owt) {
    __shared__ float tile[32][33];
    int z = blockIdx.z;
    const float* w = (z == 0) ? qw : (z == 1) ? kw : (z == 2) ? vw : ow;
    int n0 = blockIdx.x * 32, k0 = blockIdx.y * 32;
    int tx = threadIdx.x & 31, ty = threadIdx.x >> 5;
#pragma unroll
    for (int i = 0; i < 32; i += 8)
        tile[ty + i][tx] = w[(k0 + ty + i) * DMODEL + n0 + tx];
    __syncthreads();
#pragma unroll
    for (int i = 0; i < 32; i += 8) {
        float f = tile[tx][ty + i];           // = w[k0+tx][n0+ty+i]
        int k = k0 + tx, n = n0 + ty + i;
        if (z <= 1) {
            __bf16 fh = (__bf16)f;
            __bf16 fl = (__bf16)(f - (float)fh);
            int c = (n & 15) * 64 + (n >> 4);
            if (z == 0) { qwthi[c * DMODEL + k] = fh; qwtlo[c * DMODEL + k] = fl; }
            else        { kwthi[c * DMODEL + k] = fh; kwtlo[c * DMODEL + k] = fl; }
        } else if (z == 2) {
            vwt[n * DMODEL + k] = (__bf16)f;
        } else {
            int ck = (k & 15) * 64 + (k >> 4);
            owt[n * DMODEL + ck] = (__bf16)f;
        }
    }
}

// ---------------------------------------------------------------------------
// Fused QKV projection GEMM. grid (8, 32, 3).
// z=0: Q = x @ qw (split-bf16, scale log2e/32), merged [m][c] hi/lo out.
// z=1: K likewise, scale 1.
// z=2: V^T = vwt @ x^T (plain), out [bh][d][s].
// ---------------------------------------------------------------------------
__global__ __launch_bounds__(256) void qkv_gemm(
    const __bf16* __restrict__ xhi, const __bf16* __restrict__ xlo,
    const __bf16* __restrict__ qwthi, const __bf16* __restrict__ qwtlo,
    const __bf16* __restrict__ kwthi, const __bf16* __restrict__ kwtlo,
    const __bf16* __restrict__ vwt,
    __bf16* __restrict__ Qhi, __bf16* __restrict__ Qlo,
    __bf16* __restrict__ Khi, __bf16* __restrict__ Klo,
    __bf16* __restrict__ Vt) {
    __shared__ __bf16 Ash[128][32], Asl[128][32], Bsh[128][32], Bsl[128][32];
    int mode = blockIdx.z;
    int tid  = threadIdx.x;
    int wave = tid >> 6, lane = tid & 63;
    int quad = lane >> 4, l15 = lane & 15;
    int wm = (wave >> 1) * 64, wn = (wave & 1) * 64;
    int grow = lane >> 2, gcol = (lane & 3) * 8;
    const int K = DMODEL;

    if (mode < 2) {
        const __bf16* Bh = mode ? kwthi : qwthi;
        const __bf16* Bl = mode ? kwtlo : qwtlo;
        int m0 = blockIdx.y * 128, n0 = blockIdx.x * 128;
        f32x4 acc[4][4] = {};
        for (int k0 = 0; k0 < K; k0 += 32) {
            __syncthreads();
#pragma unroll
            for (int ps = 0; ps < 2; ps++) {
                int row = ps * 64 + wave * 16;
                gll16(&xhi[(m0 + row + grow) * K + k0 + gcol], &Ash[row][0]);
                gll16(&xlo[(m0 + row + grow) * K + k0 + gcol], &Asl[row][0]);
                gll16(&Bh [(n0 + row + grow) * K + k0 + gcol], &Bsh[row][0]);
                gll16(&Bl [(n0 + row + grow) * K + k0 + gcol], &Bsl[row][0]);
            }
            __syncthreads();
            bf16x8 ah[4], al[4], bh[4], bl[4];
#pragma unroll
            for (int mi = 0; mi < 4; mi++) {
                ah[mi] = *(const bf16x8*)&Ash[wm + mi * 16 + l15][quad * 8];
                al[mi] = *(const bf16x8*)&Asl[wm + mi * 16 + l15][quad * 8];
            }
#pragma unroll
            for (int ni = 0; ni < 4; ni++) {
                bh[ni] = *(const bf16x8*)&Bsh[wn + ni * 16 + l15][quad * 8];
                bl[ni] = *(const bf16x8*)&Bsl[wn + ni * 16 + l15][quad * 8];
            }
#pragma unroll
            for (int mi = 0; mi < 4; mi++)
#pragma unroll
                for (int ni = 0; ni < 4; ni++) {
                    acc[mi][ni] = __builtin_amdgcn_mfma_f32_16x16x32_bf16(ah[mi], bh[ni], acc[mi][ni], 0, 0, 0);
                    acc[mi][ni] = __builtin_amdgcn_mfma_f32_16x16x32_bf16(ah[mi], bl[ni], acc[mi][ni], 0, 0, 0);
                    acc[mi][ni] = __builtin_amdgcn_mfma_f32_16x16x32_bf16(al[mi], bh[ni], acc[mi][ni], 0, 0, 0);
                }
        }
        float oscale = mode ? 1.0f : 0.03125f * LOG2E;
        __bf16* Ohi = mode ? Khi : Qhi;
        __bf16* Olo = mode ? Klo : Qlo;
#pragma unroll
        for (int mi = 0; mi < 4; mi++)
#pragma unroll
            for (int ni = 0; ni < 4; ni++)
#pragma unroll
                for (int rg = 0; rg < 4; rg++) {
                    int m = m0 + wm + mi * 16 + quad * 4 + rg;
                    int n = n0 + wn + ni * 16 + l15;     // n == merged channel
                    float v = acc[mi][ni][rg] * oscale;
                    size_t idx = (size_t)m * DMODEL + n;
                    __bf16 vh = (__bf16)v;
                    Ohi[idx] = vh;
                    Olo[idx] = (__bf16)(v - (float)vh);
                }
    } else {
        // V^T: A = vwt (channel rows), B = xhi (x rows); C[ch][xm]
        int ch0 = blockIdx.x * 128, xm0 = blockIdx.y * 128;
        f32x4 acc[4][4] = {};
        for (int k0 = 0; k0 < K; k0 += 32) {
            __syncthreads();
#pragma unroll
            for (int ps = 0; ps < 2; ps++) {
                int row = ps * 64 + wave * 16;
                gll16(&vwt[(ch0 + row + grow) * K + k0 + gcol], &Ash[row][0]);
                gll16(&xhi[(xm0 + row + grow) * K + k0 + gcol], &Bsh[row][0]);
            }
            __syncthreads();
            bf16x8 af[4], bfr[4];
#pragma unroll
            for (int mi = 0; mi < 4; mi++)
                af[mi] = *(const bf16x8*)&Ash[wm + mi * 16 + l15][quad * 8];
#pragma unroll
            for (int ni = 0; ni < 4; ni++)
                bfr[ni] = *(const bf16x8*)&Bsh[wn + ni * 16 + l15][quad * 8];
#pragma unroll
            for (int mi = 0; mi < 4; mi++)
#pragma unroll
                for (int ni = 0; ni < 4; ni++)
                    acc[mi][ni] = __builtin_amdgcn_mfma_f32_16x16x32_bf16(
                        af[mi], bfr[ni], acc[mi][ni], 0, 0, 0);
        }
#pragma unroll
        for (int mi = 0; mi < 4; mi++)
#pragma unroll
            for (int ni = 0; ni < 4; ni++)
#pragma unroll
                for (int rg = 0; rg < 4; rg++) {
                    int ch = ch0 + wm + mi * 16 + quad * 4 + rg;
                    int xm = xm0 + wn + ni * 16 + l15;
                    int b = xm >> 11, s = xm & 2047;
                    int h = ch & 15,  d = ch >> 4;
                    Vt[((size_t)(b * NHEADS + h) * HDIM + d) * S_LEN + s] =
                        (__bf16)acc[mi][ni][rg];
                }
    }
}

// ---------------------------------------------------------------------------
// Output projection: out[m][n] = attnb[m][:] . owt[n][:], fp32 out.
// 64x128 tiles -> grid (8,64) = 512 blocks.
// ---------------------------------------------------------------------------
__global__ __launch_bounds__(256) void out_gemm(const __bf16* __restrict__ A,
                                                const __bf16* __restrict__ Bt,
                                                float* __restrict__ out) {
    __shared__ __bf16 As[64][32];
    __shared__ __bf16 Bs[128][32];
    int tid  = threadIdx.x;
    int wave = tid >> 6, lane = tid & 63;
    int quad = lane >> 4, l15 = lane & 15;
    int m0 = blockIdx.y * 64, n0 = blockIdx.x * 128;
    int wm = (wave >> 1) * 32, wn = (wave & 1) * 64;
    int grow = lane >> 2, gcol = (lane & 3) * 8;
    const int K = DMODEL;
    f32x4 acc[2][4] = {};

    for (int k0 = 0; k0 < K; k0 += 32) {
        __syncthreads();
        gll16(&A[(m0 + wave * 16 + grow) * K + k0 + gcol], &As[wave * 16][0]);
#pragma unroll
        for (int ps = 0; ps < 2; ps++) {
            int row = ps * 64 + wave * 16;
            gll16(&Bt[(n0 + row + grow) * K + k0 + gcol], &Bs[row][0]);
        }
        __syncthreads();
        bf16x8 af[2], bfr[4];
#pragma unroll
        for (int mi = 0; mi < 2; mi++)
            af[mi] = *(const bf16x8*)&As[wm + mi * 16 + l15][quad * 8];
#pragma unroll
        for (int ni = 0; ni < 4; ni++)
            bfr[ni] = *(const bf16x8*)&Bs[wn + ni * 16 + l15][quad * 8];
#pragma unroll
        for (int mi = 0; mi < 2; mi++)
#pragma unroll
            for (int ni = 0; ni < 4; ni++)
                acc[mi][ni] = __builtin_amdgcn_mfma_f32_16x16x32_bf16(
                    af[mi], bfr[ni], acc[mi][ni], 0, 0, 0);
    }

#pragma unroll
    for (int mi = 0; mi < 2; mi++)
#pragma unroll
        for (int ni = 0; ni < 4; ni++)
#pragma unroll
            for (int rg = 0; rg < 4; rg++) {
                int m = m0 + wm + mi * 16 + quad * 4 + rg;
                int n = n0 + wn + ni * 16 + l15;
                out[(size_t)m * DMODEL + n] = acc[mi][ni][rg];
            }
}

// ---------------------------------------------------------------------------
// Flash attention v7 — 128-row q-tile per block, 32 rows (2 M-frags) per wave.
// Each K/V LDS read feeds both M-frags (2x arithmetic intensity per LDS byte).
// Grid 512 = 32 bh x 16 tiles; longest tiles first; 4 heads pinned per XCD.
// K/V staged in LDS in MFMA-fragment order; exp2 softmax; ones-MFMA row-sum;
// mask only where the key tile crosses the diagonal.
// ---------------------------------------------------------------------------
__global__ __launch_bounds__(256, 3) void flash_attn(const __bf16* __restrict__ Qhi,
                                                     const __bf16* __restrict__ Qlo,
                                                     const __bf16* __restrict__ Khi,
                                                     const __bf16* __restrict__ Klo,
                                                     const __bf16* __restrict__ Vt,
                                                     __bf16* __restrict__ attn) {
    int id  = blockIdx.x;
    int xcd = id & 7, r = id >> 3;
    int bh  = xcd + 8 * (r & 3);           // 4 heads pinned per XCD
    int t   = 15 - (r >> 2);               // longest q-tiles dispatched first
    int b = bh >> 4, h = bh & 15;
    const __bf16* Qh_hi = Qhi + (size_t)b * S_LEN * DMODEL + h * HDIM;
    const __bf16* Qh_lo = Qlo + (size_t)b * S_LEN * DMODEL + h * HDIM;
    const __bf16* Kh_hi = Khi + (size_t)b * S_LEN * DMODEL + h * HDIM;
    const __bf16* Kh_lo = Klo + (size_t)b * S_LEN * DMODEL + h * HDIM;
    const __bf16* Vh    = Vt  + (size_t)bh * HDIM * S_LEN;

    int tid = threadIdx.x, wave = tid >> 6, lane = tid & 63;
    int quad = lane >> 4, l15 = lane & 15;
    int iters = 2 * t + 2;                 // keys 0 .. 128t+127

    __shared__ __bf16 KhF[8 * 64 * 8];
    __shared__ __bf16 KlF[8 * 64 * 8];
    __shared__ __bf16 VF [8 * 64 * 8];
    __shared__ __bf16 Ps[4][32][72];

    int c1  = tid >> 6, key = tid & 63;
    int inner = (c1 * 16 + (key & 15)) * 8;
    int rK    = (key >> 4);
    int kdst0 = rK * 512 + inner, kdst1 = (4 + rK) * 512 + inner;
    const __bf16* vrow = Vh + (size_t)key * S_LEN;   // dim = key var

    int q0w = t * 128 + wave * 32;
    bf16x8 aqh0[2], aqh1[2], aql0[2], aql1[2];
#pragma unroll
    for (int mi = 0; mi < 2; mi++) {
        size_t qr = (size_t)(q0w + mi * 16 + l15) * DMODEL;
        aqh0[mi] = *(const bf16x8*)&Qh_hi[qr + quad * 8];
        aqh1[mi] = *(const bf16x8*)&Qh_hi[qr + 32 + quad * 8];
        aql0[mi] = *(const bf16x8*)&Qh_lo[qr + quad * 8];
        aql1[mi] = *(const bf16x8*)&Qh_lo[qr + 32 + quad * 8];
    }

    bf16x8 ones;
#pragma unroll
    for (int j = 0; j < 8; j++) ones[j] = (__bf16)1.0f;

    uint4 pk0, pk1, pl0, pl1, pv0, pv1;
    {   // prefetch tile kt=0
        const __bf16* sk = Kh_hi + (size_t)key * DMODEL;
        const __bf16* sl = Kh_lo + (size_t)key * DMODEL;
        pk0 = *(const uint4*)(sk + c1 * 8); pk1 = *(const uint4*)(sk + c1 * 8 + 32);
        pl0 = *(const uint4*)(sl + c1 * 8); pl1 = *(const uint4*)(sl + c1 * 8 + 32);
        pv0 = *(const uint4*)(vrow + c1 * 8); pv1 = *(const uint4*)(vrow + c1 * 8 + 32);
    }

    float m[2][4] = {{-3e38f, -3e38f, -3e38f, -3e38f},
                     {-3e38f, -3e38f, -3e38f, -3e38f}};
    f32x4 o[2][4] = {};
    f32x4 ol[2] = {};

    for (int i = 0; i < iters; i++) {
        int key0 = i * 64;

        __syncthreads();
        *(uint4*)&KhF[kdst0] = pk0;  *(uint4*)&KhF[kdst1] = pk1;
        *(uint4*)&KlF[kdst0] = pl0;  *(uint4*)&KlF[kdst1] = pl1;
        *(uint4*)&VF [kdst0] = pv0;  *(uint4*)&VF [kdst1] = pv1;
        __syncthreads();

        if (i + 1 < iters) {
            int key0n = (i + 1) * 64;
            const __bf16* sk = Kh_hi + (size_t)(key0n + key) * DMODEL;
            const __bf16* sl = Kh_lo + (size_t)(key0n + key) * DMODEL;
            pk0 = *(const uint4*)(sk + c1 * 8); pk1 = *(const uint4*)(sk + c1 * 8 + 32);
            pl0 = *(const uint4*)(sl + c1 * 8); pl1 = *(const uint4*)(sl + c1 * 8 + 32);
            pv0 = *(const uint4*)(vrow + key0n + c1 * 8);
            pv1 = *(const uint4*)(vrow + key0n + c1 * 8 + 32);
        }

        // ---- S(log2 domain) = Q K^T for both M-frags; K frags read once
        f32x4 sc[2][4] = {};
#pragma unroll
        for (int ni = 0; ni < 4; ni++) {
            bf16x8 kh0 = *(const bf16x8*)&KhF[(ni * 64 + lane) * 8];
            bf16x8 kh1 = *(const bf16x8*)&KhF[((4 + ni) * 64 + lane) * 8];
            bf16x8 kl0 = *(const bf16x8*)&KlF[(ni * 64 + lane) * 8];
            bf16x8 kl1 = *(const bf16x8*)&KlF[((4 + ni) * 64 + lane) * 8];
#pragma unroll
            for (int mi = 0; mi < 2; mi++) {
                sc[mi][ni] = __builtin_amdgcn_mfma_f32_16x16x32_bf16(aqh0[mi], kh0, sc[mi][ni], 0, 0, 0);
                sc[mi][ni] = __builtin_amdgcn_mfma_f32_16x16x32_bf16(aqh1[mi], kh1, sc[mi][ni], 0, 0, 0);
                sc[mi][ni] = __builtin_amdgcn_mfma_f32_16x16x32_bf16(aqh0[mi], kl0, sc[mi][ni], 0, 0, 0);
                sc[mi][ni] = __builtin_amdgcn_mfma_f32_16x16x32_bf16(aqh1[mi], kl1, sc[mi][ni], 0, 0, 0);
                sc[mi][ni] = __builtin_amdgcn_mfma_f32_16x16x32_bf16(aql0[mi], kh0, sc[mi][ni], 0, 0, 0);
                sc[mi][ni] = __builtin_amdgcn_mfma_f32_16x16x32_bf16(aql1[mi], kh1, sc[mi][ni], 0, 0, 0);
            }
        }

        // ---- mask + online softmax per M-frag
#pragma unroll
        for (int mi = 0; mi < 2; mi++) {
            int qrb = q0w + mi * 16 + quad * 4;
            if (key0 + 63 > qrb) {
#pragma unroll
                for (int ni = 0; ni < 4; ni++) {
                    int keyi = key0 + ni * 16 + l15;
#pragma unroll
                    for (int rg = 0; rg < 4; rg++)
                        if (keyi > qrb + rg) sc[mi][ni][rg] = -1e30f;
                }
            }
#pragma unroll
            for (int rg = 0; rg < 4; rg++) {
                float mx = fmaxf(fmaxf(sc[mi][0][rg], sc[mi][1][rg]),
                                 fmaxf(sc[mi][2][rg], sc[mi][3][rg]));
#pragma unroll
                for (int mm = 1; mm < 16; mm <<= 1)
                    mx = fmaxf(mx, __shfl_xor(mx, mm, 64));
                float mnew  = fmaxf(m[mi][rg], mx);
                float alpha = __builtin_amdgcn_exp2f(m[mi][rg] - mnew);
                m[mi][rg] = mnew;
#pragma unroll
                for (int ni = 0; ni < 4; ni++) {
                    float px = __builtin_amdgcn_exp2f(sc[mi][ni][rg] - mnew);
                    Ps[wave][mi * 16 + quad * 4 + rg][ni * 16 + l15] = (__bf16)px;
                }
                ol[mi][rg] *= alpha;
#pragma unroll
                for (int ni = 0; ni < 4; ni++)
                    o[mi][ni][rg] *= alpha;
            }
        }

        // ---- O += P @ V ; l += P @ 1  (V frags read once, feed both M-frags)
#pragma unroll
        for (int step = 0; step < 2; step++) {
            bf16x8 ap0 = *(const bf16x8*)&Ps[wave][l15][step * 32 + quad * 8];
            bf16x8 ap1 = *(const bf16x8*)&Ps[wave][16 + l15][step * 32 + quad * 8];
            ol[0] = __builtin_amdgcn_mfma_f32_16x16x32_bf16(ap0, ones, ol[0], 0, 0, 0);
            ol[1] = __builtin_amdgcn_mfma_f32_16x16x32_bf16(ap1, ones, ol[1], 0, 0, 0);
#pragma unroll
            for (int ni = 0; ni < 4; ni++) {
                bf16x8 bv = *(const bf16x8*)&VF[((step * 4 + ni) * 64 + lane) * 8];
                o[0][ni] = __builtin_amdgcn_mfma_f32_16x16x32_bf16(ap0, bv, o[0][ni], 0, 0, 0);
                o[1][ni] = __builtin_amdgcn_mfma_f32_16x16x32_bf16(ap1, bv, o[1][ni], 0, 0, 0);
            }
        }
    }

    // ---- epilogue: coalesced merged-layout store
#pragma unroll
    for (int mi = 0; mi < 2; mi++)
#pragma unroll
        for (int rg = 0; rg < 4; rg++) {
            float inv = 1.0f / ol[mi][rg];
            int q = q0w + mi * 16 + quad * 4 + rg;
#pragma unroll
            for (int ni = 0; ni < 4; ni++) {
                attn[((size_t)b * S_LEN + q) * DMODEL + h * HDIM + ni * 16 + l15] =
                    (__bf16)(o[mi][ni][rg] * inv);
            }
        }
}

// ---------------------------------------------------------------------------
extern "C" void kernel_launch(void* const* d_in, const int* in_sizes, int n_in,
                              void* d_out, int out_size, void* d_ws, size_t ws_size,
                              hipStream_t stream) {
    const float* x  = (const float*)d_in[0];
    const float* qw = (const float*)d_in[1];
    const float* kw = (const float*)d_in[2];
    const float* vw = (const float*)d_in[3];
    const float* ow = (const float*)d_in[4];

    char* ws = (char*)d_ws;
    const size_t MB = 1024 * 1024;
    __bf16* xhi   = (__bf16*)(ws);             //  8 MB  [4096,1024]
    __bf16* xlo   = (__bf16*)(ws + 8 * MB);    //  8 MB  (reused as attnb later)
    __bf16* qwthi = (__bf16*)(ws + 16 * MB);   //  2 MB each
    __bf16* qwtlo = (__bf16*)(ws + 18 * MB);
    __bf16* kwthi = (__bf16*)(ws + 20 * MB);
    __bf16* kwtlo = (__bf16*)(ws + 22 * MB);
    __bf16* vwt   = (__bf16*)(ws + 24 * MB);
    __bf16* owt   = (__bf16*)(ws + 26 * MB);
    __bf16* Qhi_b = (__bf16*)(ws + 28 * MB);   //  8 MB  merged [B*S][D]
    __bf16* Qlo_b = (__bf16*)(ws + 36 * MB);
    __bf16* Khi_b = (__bf16*)(ws + 44 * MB);
    __bf16* Klo_b = (__bf16*)(ws + 52 * MB);
    __bf16* Vtb   = (__bf16*)(ws + 60 * MB);   //  8 MB  [B,H,64,S]
    __bf16* attnb = xlo;                       //  alias: xlo dead after QKV GEMMs

    conv_split<<<4096, 256, 0, stream>>>(x, xhi, xlo, 4096 * 1024 / 4);
    transpose_all<<<dim3(32, 32, 4), 256, 0, stream>>>(
        qw, kw, vw, ow, qwthi, qwtlo, kwthi, kwtlo, vwt, owt);

    qkv_gemm<<<dim3(8, 32, 3), 256, 0, stream>>>(
        xhi, xlo, qwthi, qwtlo, kwthi, kwtlo, vwt,
        Qhi_b, Qlo_b, Khi_b, Klo_b, Vtb);

    flash_attn<<<512, 256, 0, stream>>>(Qhi_b, Qlo_b, Khi_b, Klo_b, Vtb, attnb);

    out_gemm<<<dim3(8, 64), 256, 0, stream>>>(attnb, owt, (float*)d_out);
}

// Round 9
// 275.253 us; speedup vs baseline: 1.1835x; 1.1835x over previous
//
#include <hip/hip_runtime.h>

// ---------------------------------------------------------------------------
// MultiHeadAttention: B=2, S=2048, D=1024, H=16, hd=64
// Interleaved head split: Q[b,h,s,d] = proj[b,s, d*16+h]; scale = 1/32.
// Precision: split-bf16 (hi+lo) emulated-fp32 for Q/K path. V/attn/out plain bf16.
// v8: flash reverted to v6 (64-row tiles, 1024 blocks @4/CU — v7's fat
// imbalanced blocks halved occupancy). GEMM phase: Q and K projections fused
// into one block (shared xhi/xlo staging: 48KB staged per 96 MFMAs vs
// 32KB/48; x L2 traffic halved). conv_split + weight transposes fused.
// ---------------------------------------------------------------------------

typedef __bf16 bf16x8 __attribute__((ext_vector_type(8)));
typedef float  f32x4  __attribute__((ext_vector_type(4)));

#define S_LEN  2048
#define DMODEL 1024
#define NHEADS 16
#define HDIM   64
#define LOG2E  1.44269504088896340736f

__device__ __forceinline__ void gll16(const __bf16* g, __bf16* l) {
    __builtin_amdgcn_global_load_lds(
        (const __attribute__((address_space(1))) unsigned int*)g,
        (__attribute__((address_space(3))) unsigned int*)l, 16, 0, 0);
}

// ---------------------------------------------------------------------------
// Fused prep: id<4096 -> f32->(hi,lo) conv of x; else weight transposes.
// transpose z=0: qw split col-permuted; z=1: kw; z=2: vw plain; z=3: ow
// k-permuted. perm(i) = (i&15)*64 + (i>>4).
// ---------------------------------------------------------------------------
__global__ __launch_bounds__(256) void prep_all(
    const float* __restrict__ x,
    const float* __restrict__ qw, const float* __restrict__ kw,
    const float* __restrict__ vw, const float* __restrict__ ow,
    __bf16* __restrict__ xhi, __bf16* __restrict__ xlo,
    __bf16* __restrict__ qwthi, __bf16* __restrict__ qwtlo,
    __bf16* __restrict__ kwthi, __bf16* __restrict__ kwtlo,
    __bf16* __restrict__ vwt,  __bf16* __restrict__ owt) {
    __shared__ float tile[32][33];
    int id = blockIdx.x;
    if (id < 4096) {
        int i = id * 256 + threadIdx.x;
        float4 v = ((const float4*)x)[i];
        __bf16 h0 = (__bf16)v.x, h1 = (__bf16)v.y, h2 = (__bf16)v.z, h3 = (__bf16)v.w;
        ushort4 hh, ll;
        hh.x = __builtin_bit_cast(unsigned short, h0);
        hh.y = __builtin_bit_cast(unsigned short, h1);
        hh.z = __builtin_bit_cast(unsigned short, h2);
        hh.w = __builtin_bit_cast(unsigned short, h3);
        ll.x = __builtin_bit_cast(unsigned short, (__bf16)(v.x - (float)h0));
        ll.y = __builtin_bit_cast(unsigned short, (__bf16)(v.y - (float)h1));
        ll.z = __builtin_bit_cast(unsigned short, (__bf16)(v.z - (float)h2));
        ll.w = __builtin_bit_cast(unsigned short, (__bf16)(v.w - (float)h3));
        ((ushort4*)xhi)[i] = hh;
        ((ushort4*)xlo)[i] = ll;
        return;
    }
    int rid = id - 4096;
    int z = rid >> 10;                       // 0..3
    int bx = rid & 31, by = (rid >> 5) & 31;
    const float* w = (z == 0) ? qw : (z == 1) ? kw : (z == 2) ? vw : ow;
    int n0 = bx * 32, k0 = by * 32;
    int tx = threadIdx.x & 31, ty = threadIdx.x >> 5;
#pragma unroll
    for (int i = 0; i < 32; i += 8)
        tile[ty + i][tx] = w[(k0 + ty + i) * DMODEL + n0 + tx];
    __syncthreads();
#pragma unroll
    for (int i = 0; i < 32; i += 8) {
        float f = tile[tx][ty + i];           // = w[k0+tx][n0+ty+i]
        int k = k0 + tx, n = n0 + ty + i;
        if (z <= 1) {
            __bf16 fh = (__bf16)f;
            __bf16 fl = (__bf16)(f - (float)fh);
            int c = (n & 15) * 64 + (n >> 4);
            if (z == 0) { qwthi[c * DMODEL + k] = fh; qwtlo[c * DMODEL + k] = fl; }
            else        { kwthi[c * DMODEL + k] = fh; kwtlo[c * DMODEL + k] = fl; }
        } else if (z == 2) {
            vwt[n * DMODEL + k] = (__bf16)f;
        } else {
            int ck = (k & 15) * 64 + (k >> 4);
            owt[n * DMODEL + ck] = (__bf16)f;
        }
    }
}

// ---------------------------------------------------------------------------
// QKV projections. grid (8, 32, 2).
// z=0: FUSED Q+K split-bf16 GEMM — one A-tile staging feeds both B sets.
//      Q scale log2e/32; K scale 1. Merged [m][c] hi/lo outputs.
// z=1: V^T = vwt @ x^T (plain bf16), out [bh][d][s].
// ---------------------------------------------------------------------------
__global__ __launch_bounds__(256) void qkv_gemm(
    const __bf16* __restrict__ xhi, const __bf16* __restrict__ xlo,
    const __bf16* __restrict__ qwthi, const __bf16* __restrict__ qwtlo,
    const __bf16* __restrict__ kwthi, const __bf16* __restrict__ kwtlo,
    const __bf16* __restrict__ vwt,
    __bf16* __restrict__ Qhi, __bf16* __restrict__ Qlo,
    __bf16* __restrict__ Khi, __bf16* __restrict__ Klo,
    __bf16* __restrict__ Vt) {
    __shared__ __bf16 Ash[128][32], Asl[128][32];
    __shared__ __bf16 Bqh[128][32], Bql[128][32], Bkh[128][32], Bkl[128][32];
    int tid  = threadIdx.x;
    int wave = tid >> 6, lane = tid & 63;
    int quad = lane >> 4, l15 = lane & 15;
    int wm = (wave >> 1) * 64, wn = (wave & 1) * 64;
    int grow = lane >> 2, gcol = (lane & 3) * 8;
    const int K = DMODEL;

    if (blockIdx.z == 0) {
        int m0 = blockIdx.y * 128, n0 = blockIdx.x * 128;
        f32x4 accQ[4][4] = {}, accK[4][4] = {};
        for (int k0 = 0; k0 < K; k0 += 32) {
            __syncthreads();
#pragma unroll
            for (int ps = 0; ps < 2; ps++) {
                int row = ps * 64 + wave * 16;
                gll16(&xhi  [(m0 + row + grow) * K + k0 + gcol], &Ash[row][0]);
                gll16(&xlo  [(m0 + row + grow) * K + k0 + gcol], &Asl[row][0]);
                gll16(&qwthi[(n0 + row + grow) * K + k0 + gcol], &Bqh[row][0]);
                gll16(&qwtlo[(n0 + row + grow) * K + k0 + gcol], &Bql[row][0]);
                gll16(&kwthi[(n0 + row + grow) * K + k0 + gcol], &Bkh[row][0]);
                gll16(&kwtlo[(n0 + row + grow) * K + k0 + gcol], &Bkl[row][0]);
            }
            __syncthreads();
            bf16x8 ah[4], al[4];
#pragma unroll
            for (int mi = 0; mi < 4; mi++) {
                ah[mi] = *(const bf16x8*)&Ash[wm + mi * 16 + l15][quad * 8];
                al[mi] = *(const bf16x8*)&Asl[wm + mi * 16 + l15][quad * 8];
            }
#pragma unroll
            for (int ni = 0; ni < 4; ni++) {
                bf16x8 bh = *(const bf16x8*)&Bqh[wn + ni * 16 + l15][quad * 8];
                bf16x8 bl = *(const bf16x8*)&Bql[wn + ni * 16 + l15][quad * 8];
#pragma unroll
                for (int mi = 0; mi < 4; mi++) {
                    accQ[mi][ni] = __builtin_amdgcn_mfma_f32_16x16x32_bf16(ah[mi], bh, accQ[mi][ni], 0, 0, 0);
                    accQ[mi][ni] = __builtin_amdgcn_mfma_f32_16x16x32_bf16(ah[mi], bl, accQ[mi][ni], 0, 0, 0);
                    accQ[mi][ni] = __builtin_amdgcn_mfma_f32_16x16x32_bf16(al[mi], bh, accQ[mi][ni], 0, 0, 0);
                }
                bh = *(const bf16x8*)&Bkh[wn + ni * 16 + l15][quad * 8];
                bl = *(const bf16x8*)&Bkl[wn + ni * 16 + l15][quad * 8];
#pragma unroll
                for (int mi = 0; mi < 4; mi++) {
                    accK[mi][ni] = __builtin_amdgcn_mfma_f32_16x16x32_bf16(ah[mi], bh, accK[mi][ni], 0, 0, 0);
                    accK[mi][ni] = __builtin_amdgcn_mfma_f32_16x16x32_bf16(ah[mi], bl, accK[mi][ni], 0, 0, 0);
                    accK[mi][ni] = __builtin_amdgcn_mfma_f32_16x16x32_bf16(al[mi], bh, accK[mi][ni], 0, 0, 0);
                }
            }
        }
        const float qscale = 0.03125f * LOG2E;
#pragma unroll
        for (int mi = 0; mi < 4; mi++)
#pragma unroll
            for (int ni = 0; ni < 4; ni++)
#pragma unroll
                for (int rg = 0; rg < 4; rg++) {
                    int m = m0 + wm + mi * 16 + quad * 4 + rg;
                    int n = n0 + wn + ni * 16 + l15;     // n == merged channel
                    size_t idx = (size_t)m * DMODEL + n;
                    float vq = accQ[mi][ni][rg] * qscale;
                    __bf16 vqh = (__bf16)vq;
                    Qhi[idx] = vqh;
                    Qlo[idx] = (__bf16)(vq - (float)vqh);
                    float vk = accK[mi][ni][rg];
                    __bf16 vkh = (__bf16)vk;
                    Khi[idx] = vkh;
                    Klo[idx] = (__bf16)(vk - (float)vkh);
                }
    } else {
        // V^T: A = vwt (channel rows), B = xhi (x rows); C[ch][xm]
        int ch0 = blockIdx.x * 128, xm0 = blockIdx.y * 128;
        f32x4 acc[4][4] = {};
        for (int k0 = 0; k0 < K; k0 += 32) {
            __syncthreads();
#pragma unroll
            for (int ps = 0; ps < 2; ps++) {
                int row = ps * 64 + wave * 16;
                gll16(&vwt[(ch0 + row + grow) * K + k0 + gcol], &Ash[row][0]);
                gll16(&xhi[(xm0 + row + grow) * K + k0 + gcol], &Bqh[row][0]);
            }
            __syncthreads();
            bf16x8 af[4], bfr[4];
#pragma unroll
            for (int mi = 0; mi < 4; mi++)
                af[mi] = *(const bf16x8*)&Ash[wm + mi * 16 + l15][quad * 8];
#pragma unroll
            for (int ni = 0; ni < 4; ni++)
                bfr[ni] = *(const bf16x8*)&Bqh[wn + ni * 16 + l15][quad * 8];
#pragma unroll
            for (int mi = 0; mi < 4; mi++)
#pragma unroll
                for (int ni = 0; ni < 4; ni++)
                    acc[mi][ni] = __builtin_amdgcn_mfma_f32_16x16x32_bf16(
                        af[mi], bfr[ni], acc[mi][ni], 0, 0, 0);
        }
#pragma unroll
        for (int mi = 0; mi < 4; mi++)
#pragma unroll
            for (int ni = 0; ni < 4; ni++)
#pragma unroll
                for (int rg = 0; rg < 4; rg++) {
                    int ch = ch0 + wm + mi * 16 + quad * 4 + rg;
                    int xm = xm0 + wn + ni * 16 + l15;
                    int b = xm >> 11, s = xm & 2047;
                    int h = ch & 15,  d = ch >> 4;
                    Vt[((size_t)(b * NHEADS + h) * HDIM + d) * S_LEN + s] =
                        (__bf16)acc[mi][ni][rg];
                }
    }
}

// ---------------------------------------------------------------------------
// Output projection: out[m][n] = attnb[m][:] . owt[n][:], fp32 out.
// 64x128 tiles -> grid (8,64) = 512 blocks.
// ---------------------------------------------------------------------------
__global__ __launch_bounds__(256) void out_gemm(const __bf16* __restrict__ A,
                                                const __bf16* __restrict__ Bt,
                                                float* __restrict__ out) {
    __shared__ __bf16 As[64][32];
    __shared__ __bf16 Bs[128][32];
    int tid  = threadIdx.x;
    int wave = tid >> 6, lane = tid & 63;
    int quad = lane >> 4, l15 = lane & 15;
    int m0 = blockIdx.y * 64, n0 = blockIdx.x * 128;
    int wm = (wave >> 1) * 32, wn = (wave & 1) * 64;
    int grow = lane >> 2, gcol = (lane & 3) * 8;
    const int K = DMODEL;
    f32x4 acc[2][4] = {};

    for (int k0 = 0; k0 < K; k0 += 32) {
        __syncthreads();
        gll16(&A[(m0 + wave * 16 + grow) * K + k0 + gcol], &As[wave * 16][0]);
#pragma unroll
        for (int ps = 0; ps < 2; ps++) {
            int row = ps * 64 + wave * 16;
            gll16(&Bt[(n0 + row + grow) * K + k0 + gcol], &Bs[row][0]);
        }
        __syncthreads();
        bf16x8 af[2], bfr[4];
#pragma unroll
        for (int mi = 0; mi < 2; mi++)
            af[mi] = *(const bf16x8*)&As[wm + mi * 16 + l15][quad * 8];
#pragma unroll
        for (int ni = 0; ni < 4; ni++)
            bfr[ni] = *(const bf16x8*)&Bs[wn + ni * 16 + l15][quad * 8];
#pragma unroll
        for (int mi = 0; mi < 2; mi++)
#pragma unroll
            for (int ni = 0; ni < 4; ni++)
                acc[mi][ni] = __builtin_amdgcn_mfma_f32_16x16x32_bf16(
                    af[mi], bfr[ni], acc[mi][ni], 0, 0, 0);
    }

#pragma unroll
    for (int mi = 0; mi < 2; mi++)
#pragma unroll
        for (int ni = 0; ni < 4; ni++)
#pragma unroll
            for (int rg = 0; rg < 4; rg++) {
                int m = m0 + wm + mi * 16 + quad * 4 + rg;
                int n = n0 + wn + ni * 16 + l15;
                out[(size_t)m * DMODEL + n] = acc[mi][ni][rg];
            }
}

// ---------------------------------------------------------------------------
// Flash attention (v6, proven) — one block per 64-row q-tile. Grid 1024 =
// 4 blocks/CU; longest tiles dispatched first; 4 heads pinned per XCD.
// Q/K merged [b*2048+s][h*64+d] (hi/lo, Q pre-scaled log2e/32); V^T [bh][d][s].
// K/V staged in LDS in MFMA-fragment order; exp2 softmax; ones-MFMA row-sum;
// diag-only mask. Output attnb merged (coalesced).
// ---------------------------------------------------------------------------
__global__ __launch_bounds__(256, 4) void flash_attn(const __bf16* __restrict__ Qhi,
                                                     const __bf16* __restrict__ Qlo,
                                                     const __bf16* __restrict__ Khi,
                                                     const __bf16* __restrict__ Klo,
                                                     const __bf16* __restrict__ Vt,
                                                     __bf16* __restrict__ attn) {
    int id  = blockIdx.x;
    int xcd = id & 7, r = id >> 3;
    int bh  = xcd + 8 * (r & 3);           // 4 heads pinned per XCD
    int t   = 31 - (r >> 2);               // longest q-tiles dispatched first
    int b = bh >> 4, h = bh & 15;
    const __bf16* Qh_hi = Qhi + (size_t)b * S_LEN * DMODEL + h * HDIM;
    const __bf16* Qh_lo = Qlo + (size_t)b * S_LEN * DMODEL + h * HDIM;
    const __bf16* Kh_hi = Khi + (size_t)b * S_LEN * DMODEL + h * HDIM;
    const __bf16* Kh_lo = Klo + (size_t)b * S_LEN * DMODEL + h * HDIM;
    const __bf16* Vh    = Vt  + (size_t)bh * HDIM * S_LEN;

    int tid = threadIdx.x, wave = tid >> 6, lane = tid & 63;
    int quad = lane >> 4, l15 = lane & 15;
    int iters = t + 1;

    __shared__ __bf16 KhF[8 * 64 * 8];
    __shared__ __bf16 KlF[8 * 64 * 8];
    __shared__ __bf16 VF [8 * 64 * 8];
    __shared__ __bf16 Ps[4][16][72];

    int c1  = tid >> 6, key = tid & 63;
    int inner = (c1 * 16 + (key & 15)) * 8;
    int rK    = (key >> 4);
    int kdst0 = rK * 512 + inner, kdst1 = (4 + rK) * 512 + inner;
    const __bf16* vrow = Vh + (size_t)key * S_LEN;   // dim = key var

    int q0w = t * 64 + wave * 16;
    bf16x8 aqh0 = *(const bf16x8*)&Qh_hi[(size_t)(q0w + l15) * DMODEL + quad * 8];
    bf16x8 aqh1 = *(const bf16x8*)&Qh_hi[(size_t)(q0w + l15) * DMODEL + 32 + quad * 8];
    bf16x8 aql0 = *(const bf16x8*)&Qh_lo[(size_t)(q0w + l15) * DMODEL + quad * 8];
    bf16x8 aql1 = *(const bf16x8*)&Qh_lo[(size_t)(q0w + l15) * DMODEL + 32 + quad * 8];

    bf16x8 ones;
#pragma unroll
    for (int j = 0; j < 8; j++) ones[j] = (__bf16)1.0f;

    uint4 pk0, pk1, pl0, pl1, pv0, pv1;
    {   // prefetch tile kt=0
        const __bf16* sk = Kh_hi + (size_t)key * DMODEL;
        const __bf16* sl = Kh_lo + (size_t)key * DMODEL;
        pk0 = *(const uint4*)(sk + c1 * 8); pk1 = *(const uint4*)(sk + c1 * 8 + 32);
        pl0 = *(const uint4*)(sl + c1 * 8); pl1 = *(const uint4*)(sl + c1 * 8 + 32);
        pv0 = *(const uint4*)(vrow + c1 * 8); pv1 = *(const uint4*)(vrow + c1 * 8 + 32);
    }

    float m[4] = {-3e38f, -3e38f, -3e38f, -3e38f};
    f32x4 o[4] = {};
    f32x4 ol = {};
    int qrb = q0w + quad * 4;

    for (int i = 0; i < iters; i++) {
        int key0 = i * 64;
        bool diag = (i == iters - 1);

        __syncthreads();
        *(uint4*)&KhF[kdst0] = pk0;  *(uint4*)&KhF[kdst1] = pk1;
        *(uint4*)&KlF[kdst0] = pl0;  *(uint4*)&KlF[kdst1] = pl1;
        *(uint4*)&VF [kdst0] = pv0;  *(uint4*)&VF [kdst1] = pv1;
        __syncthreads();

        if (i + 1 < iters) {
            int key0n = (i + 1) * 64;
            const __bf16* sk = Kh_hi + (size_t)(key0n + key) * DMODEL;
            const __bf16* sl = Kh_lo + (size_t)(key0n + key) * DMODEL;
            pk0 = *(const uint4*)(sk + c1 * 8); pk1 = *(const uint4*)(sk + c1 * 8 + 32);
            pl0 = *(const uint4*)(sl + c1 * 8); pl1 = *(const uint4*)(sl + c1 * 8 + 32);
            pv0 = *(const uint4*)(vrow + key0n + c1 * 8);
            pv1 = *(const uint4*)(vrow + key0n + c1 * 8 + 32);
        }

        // ---- S(log2 domain) = Q K^T, split-bf16: hi.hi + hi.lo + lo.hi
        f32x4 sc[4] = {};
#pragma unroll
        for (int ni = 0; ni < 4; ni++) {
            bf16x8 kh0 = *(const bf16x8*)&KhF[(ni * 64 + lane) * 8];
            bf16x8 kh1 = *(const bf16x8*)&KhF[((4 + ni) * 64 + lane) * 8];
            bf16x8 kl0 = *(const bf16x8*)&KlF[(ni * 64 + lane) * 8];
            bf16x8 kl1 = *(const bf16x8*)&KlF[((4 + ni) * 64 + lane) * 8];
            sc[ni] = __builtin_amdgcn_mfma_f32_16x16x32_bf16(aqh0, kh0, sc[ni], 0, 0, 0);
            sc[ni] = __builtin_amdgcn_mfma_f32_16x16x32_bf16(aqh1, kh1, sc[ni], 0, 0, 0);
            sc[ni] = __builtin_amdgcn_mfma_f32_16x16x32_bf16(aqh0, kl0, sc[ni], 0, 0, 0);
            sc[ni] = __builtin_amdgcn_mfma_f32_16x16x32_bf16(aqh1, kl1, sc[ni], 0, 0, 0);
            sc[ni] = __builtin_amdgcn_mfma_f32_16x16x32_bf16(aql0, kh0, sc[ni], 0, 0, 0);
            sc[ni] = __builtin_amdgcn_mfma_f32_16x16x32_bf16(aql1, kh1, sc[ni], 0, 0, 0);
        }

        if (diag) {
#pragma unroll
            for (int ni = 0; ni < 4; ni++) {
                int keyi = key0 + ni * 16 + l15;
#pragma unroll
                for (int rg = 0; rg < 4; rg++)
                    if (keyi > qrb + rg) sc[ni][rg] = -1e30f;
            }
        }

#pragma unroll
        for (int rg = 0; rg < 4; rg++) {
            float mx = fmaxf(fmaxf(sc[0][rg], sc[1][rg]),
                             fmaxf(sc[2][rg], sc[3][rg]));
#pragma unroll
            for (int mm = 1; mm < 16; mm <<= 1)
                mx = fmaxf(mx, __shfl_xor(mx, mm, 64));
            float mnew  = fmaxf(m[rg], mx);
            float alpha = __builtin_amdgcn_exp2f(m[rg] - mnew);
            m[rg] = mnew;
#pragma unroll
            for (int ni = 0; ni < 4; ni++) {
                float px = __builtin_amdgcn_exp2f(sc[ni][rg] - mnew);
                Ps[wave][quad * 4 + rg][ni * 16 + l15] = (__bf16)px;
            }
            ol[rg] *= alpha;
#pragma unroll
            for (int ni = 0; ni < 4; ni++)
                o[ni][rg] *= alpha;
        }

#pragma unroll
        for (int step = 0; step < 2; step++) {
            bf16x8 ap = *(const bf16x8*)&Ps[wave][l15][step * 32 + quad * 8];
            ol = __builtin_amdgcn_mfma_f32_16x16x32_bf16(ap, ones, ol, 0, 0, 0);
#pragma unroll
            for (int ni = 0; ni < 4; ni++) {
                bf16x8 bv = *(const bf16x8*)&VF[((step * 4 + ni) * 64 + lane) * 8];
                o[ni] = __builtin_amdgcn_mfma_f32_16x16x32_bf16(ap, bv, o[ni], 0, 0, 0);
            }
        }
    }

    // ---- epilogue: coalesced merged-layout store
#pragma unroll
    for (int rg = 0; rg < 4; rg++) {
        float inv = 1.0f / ol[rg];
        int q = q0w + quad * 4 + rg;
#pragma unroll
        for (int ni = 0; ni < 4; ni++) {
            attn[((size_t)b * S_LEN + q) * DMODEL + h * HDIM + ni * 16 + l15] =
                (__bf16)(o[ni][rg] * inv);
        }
    }
}

// ---------------------------------------------------------------------------
extern "C" void kernel_launch(void* const* d_in, const int* in_sizes, int n_in,
                              void* d_out, int out_size, void* d_ws, size_t ws_size,
                              hipStream_t stream) {
    const float* x  = (const float*)d_in[0];
    const float* qw = (const float*)d_in[1];
    const float* kw = (const float*)d_in[2];
    const float* vw = (const float*)d_in[3];
    const float* ow = (const float*)d_in[4];

    char* ws = (char*)d_ws;
    const size_t MB = 1024 * 1024;
    __bf16* xhi   = (__bf16*)(ws);             //  8 MB  [4096,1024]
    __bf16* xlo   = (__bf16*)(ws + 8 * MB);    //  8 MB  (reused as attnb later)
    __bf16* qwthi = (__bf16*)(ws + 16 * MB);   //  2 MB each
    __bf16* qwtlo = (__bf16*)(ws + 18 * MB);
    __bf16* kwthi = (__bf16*)(ws + 20 * MB);
    __bf16* kwtlo = (__bf16*)(ws + 22 * MB);
    __bf16* vwt   = (__bf16*)(ws + 24 * MB);
    __bf16* owt   = (__bf16*)(ws + 26 * MB);
    __bf16* Qhi_b = (__bf16*)(ws + 28 * MB);   //  8 MB  merged [B*S][D]
    __bf16* Qlo_b = (__bf16*)(ws + 36 * MB);
    __bf16* Khi_b = (__bf16*)(ws + 44 * MB);
    __bf16* Klo_b = (__bf16*)(ws + 52 * MB);
    __bf16* Vtb   = (__bf16*)(ws + 60 * MB);   //  8 MB  [B,H,64,S]
    __bf16* attnb = xlo;                       //  alias: xlo dead after QKV GEMMs

    prep_all<<<8192, 256, 0, stream>>>(x, qw, kw, vw, ow,
                                       xhi, xlo, qwthi, qwtlo, kwthi, kwtlo,
                                       vwt, owt);

    qkv_gemm<<<dim3(8, 32, 2), 256, 0, stream>>>(
        xhi, xlo, qwthi, qwtlo, kwthi, kwtlo, vwt,
        Qhi_b, Qlo_b, Khi_b, Klo_b, Vtb);

    flash_attn<<<1024, 256, 0, stream>>>(Qhi_b, Qlo_b, Khi_b, Klo_b, Vtb, attnb);

    out_gemm<<<dim3(8, 64), 256, 0, stream>>>(attnb, owt, (float*)d_out);
}

// Round 10
// 248.027 us; speedup vs baseline: 1.3135x; 1.1098x over previous
//
#include <hip/hip_runtime.h>

// ---------------------------------------------------------------------------
// MultiHeadAttention: B=2, S=2048, D=1024, H=16, hd=64
// Interleaved head split: Q[b,h,s,d] = proj[b,s, d*16+h]; scale = 1/32.
// Precision: split-bf16 (hi+lo) emulated-fp32 for Q/K path. V/attn/out plain bf16.
// v9: qkv un-fused (v8's fused Q+K needed 176 VGPR -> 11% occupancy). All
// GEMM LDS tiles get a source-chunk swizzle so ds_read_b128 fragment reads
// are 2-way (free) instead of 8-way (2.94x): LDS[r][slot] holds global chunk
// (slot-(r>>1))&3; staging lane loads chunk ((lane&3)-((lane>>3)&3))&3; frag
// reads use slot (quad+(l15>>1))&3. Flash = v6 (proven 82us). Prep fused.
// ---------------------------------------------------------------------------

typedef __bf16 bf16x8 __attribute__((ext_vector_type(8)));
typedef float  f32x4  __attribute__((ext_vector_type(4)));

#define S_LEN  2048
#define DMODEL 1024
#define NHEADS 16
#define HDIM   64
#define LOG2E  1.44269504088896340736f

__device__ __forceinline__ void gll16(const __bf16* g, __bf16* l) {
    __builtin_amdgcn_global_load_lds(
        (const __attribute__((address_space(1))) unsigned int*)g,
        (__attribute__((address_space(3))) unsigned int*)l, 16, 0, 0);
}

// ---------------------------------------------------------------------------
// Fused prep: id<4096 -> f32->(hi,lo) conv of x; else weight transposes.
// z=0: qw split col-permuted; z=1: kw; z=2: vw plain; z=3: ow k-permuted.
// perm(i) = (i&15)*64 + (i>>4).
// ---------------------------------------------------------------------------
__global__ __launch_bounds__(256) void prep_all(
    const float* __restrict__ x,
    const float* __restrict__ qw, const float* __restrict__ kw,
    const float* __restrict__ vw, const float* __restrict__ ow,
    __bf16* __restrict__ xhi, __bf16* __restrict__ xlo,
    __bf16* __restrict__ qwthi, __bf16* __restrict__ qwtlo,
    __bf16* __restrict__ kwthi, __bf16* __restrict__ kwtlo,
    __bf16* __restrict__ vwt,  __bf16* __restrict__ owt) {
    __shared__ float tile[32][33];
    int id = blockIdx.x;
    if (id < 4096) {
        int i = id * 256 + threadIdx.x;
        float4 v = ((const float4*)x)[i];
        __bf16 h0 = (__bf16)v.x, h1 = (__bf16)v.y, h2 = (__bf16)v.z, h3 = (__bf16)v.w;
        ushort4 hh, ll;
        hh.x = __builtin_bit_cast(unsigned short, h0);
        hh.y = __builtin_bit_cast(unsigned short, h1);
        hh.z = __builtin_bit_cast(unsigned short, h2);
        hh.w = __builtin_bit_cast(unsigned short, h3);
        ll.x = __builtin_bit_cast(unsigned short, (__bf16)(v.x - (float)h0));
        ll.y = __builtin_bit_cast(unsigned short, (__bf16)(v.y - (float)h1));
        ll.z = __builtin_bit_cast(unsigned short, (__bf16)(v.z - (float)h2));
        ll.w = __builtin_bit_cast(unsigned short, (__bf16)(v.w - (float)h3));
        ((ushort4*)xhi)[i] = hh;
        ((ushort4*)xlo)[i] = ll;
        return;
    }
    int rid = id - 4096;
    int z = rid >> 10;                       // 0..3
    int bx = rid & 31, by = (rid >> 5) & 31;
    const float* w = (z == 0) ? qw : (z == 1) ? kw : (z == 2) ? vw : ow;
    int n0 = bx * 32, k0 = by * 32;
    int tx = threadIdx.x & 31, ty = threadIdx.x >> 5;
#pragma unroll
    for (int i = 0; i < 32; i += 8)
        tile[ty + i][tx] = w[(k0 + ty + i) * DMODEL + n0 + tx];
    __syncthreads();
#pragma unroll
    for (int i = 0; i < 32; i += 8) {
        float f = tile[tx][ty + i];           // = w[k0+tx][n0+ty+i]
        int k = k0 + tx, n = n0 + ty + i;
        if (z <= 1) {
            __bf16 fh = (__bf16)f;
            __bf16 fl = (__bf16)(f - (float)fh);
            int c = (n & 15) * 64 + (n >> 4);
            if (z == 0) { qwthi[c * DMODEL + k] = fh; qwtlo[c * DMODEL + k] = fl; }
            else        { kwthi[c * DMODEL + k] = fh; kwtlo[c * DMODEL + k] = fl; }
        } else if (z == 2) {
            vwt[n * DMODEL + k] = (__bf16)f;
        } else {
            int ck = (k & 15) * 64 + (k >> 4);
            owt[n * DMODEL + ck] = (__bf16)f;
        }
    }
}

// ---------------------------------------------------------------------------
// QKV projections. grid (8, 32, 3), LDS chunk-swizzled (2-way frag reads).
// z=0: Q = x @ qw (split-bf16, scale log2e/32), merged [m][c] hi/lo out.
// z=1: K likewise, scale 1.
// z=2: V^T = vwt @ x^T (plain), out [bh][d][s].
// ---------------------------------------------------------------------------
__global__ __launch_bounds__(256) void qkv_gemm(
    const __bf16* __restrict__ xhi, const __bf16* __restrict__ xlo,
    const __bf16* __restrict__ qwthi, const __bf16* __restrict__ qwtlo,
    const __bf16* __restrict__ kwthi, const __bf16* __restrict__ kwtlo,
    const __bf16* __restrict__ vwt,
    __bf16* __restrict__ Qhi, __bf16* __restrict__ Qlo,
    __bf16* __restrict__ Khi, __bf16* __restrict__ Klo,
    __bf16* __restrict__ Vt) {
    __shared__ __bf16 Ash[128][32], Asl[128][32], Bsh[128][32], Bsl[128][32];
    int mode = blockIdx.z;
    int tid  = threadIdx.x;
    int wave = tid >> 6, lane = tid & 63;
    int quad = lane >> 4, l15 = lane & 15;
    int wm = (wave >> 1) * 64, wn = (wave & 1) * 64;
    int grow = lane >> 2;
    int gcol = (((lane & 3) - ((lane >> 3) & 3)) & 3) * 8;   // swizzled source chunk
    int sA   = ((quad + (l15 >> 1)) & 3) * 8;                // swizzled frag slot
    const int K = DMODEL;

    if (mode < 2) {
        const __bf16* Bh = mode ? kwthi : qwthi;
        const __bf16* Bl = mode ? kwtlo : qwtlo;
        int m0 = blockIdx.y * 128, n0 = blockIdx.x * 128;
        f32x4 acc[4][4] = {};
        for (int k0 = 0; k0 < K; k0 += 32) {
            __syncthreads();
#pragma unroll
            for (int ps = 0; ps < 2; ps++) {
                int row = ps * 64 + wave * 16;
                gll16(&xhi[(m0 + row + grow) * K + k0 + gcol], &Ash[row][0]);
                gll16(&xlo[(m0 + row + grow) * K + k0 + gcol], &Asl[row][0]);
                gll16(&Bh [(n0 + row + grow) * K + k0 + gcol], &Bsh[row][0]);
                gll16(&Bl [(n0 + row + grow) * K + k0 + gcol], &Bsl[row][0]);
            }
            __syncthreads();
            bf16x8 ah[4], al[4], bh[4], bl[4];
#pragma unroll
            for (int mi = 0; mi < 4; mi++) {
                ah[mi] = *(const bf16x8*)&Ash[wm + mi * 16 + l15][sA];
                al[mi] = *(const bf16x8*)&Asl[wm + mi * 16 + l15][sA];
            }
#pragma unroll
            for (int ni = 0; ni < 4; ni++) {
                bh[ni] = *(const bf16x8*)&Bsh[wn + ni * 16 + l15][sA];
                bl[ni] = *(const bf16x8*)&Bsl[wn + ni * 16 + l15][sA];
            }
#pragma unroll
            for (int mi = 0; mi < 4; mi++)
#pragma unroll
                for (int ni = 0; ni < 4; ni++) {
                    acc[mi][ni] = __builtin_amdgcn_mfma_f32_16x16x32_bf16(ah[mi], bh[ni], acc[mi][ni], 0, 0, 0);
                    acc[mi][ni] = __builtin_amdgcn_mfma_f32_16x16x32_bf16(ah[mi], bl[ni], acc[mi][ni], 0, 0, 0);
                    acc[mi][ni] = __builtin_amdgcn_mfma_f32_16x16x32_bf16(al[mi], bh[ni], acc[mi][ni], 0, 0, 0);
                }
        }
        float oscale = mode ? 1.0f : 0.03125f * LOG2E;
        __bf16* Ohi = mode ? Khi : Qhi;
        __bf16* Olo = mode ? Klo : Qlo;
#pragma unroll
        for (int mi = 0; mi < 4; mi++)
#pragma unroll
            for (int ni = 0; ni < 4; ni++)
#pragma unroll
                for (int rg = 0; rg < 4; rg++) {
                    int m = m0 + wm + mi * 16 + quad * 4 + rg;
                    int n = n0 + wn + ni * 16 + l15;     // n == merged channel
                    float v = acc[mi][ni][rg] * oscale;
                    size_t idx = (size_t)m * DMODEL + n;
                    __bf16 vh = (__bf16)v;
                    Ohi[idx] = vh;
                    Olo[idx] = (__bf16)(v - (float)vh);
                }
    } else {
        // V^T: A = vwt (channel rows), B = xhi (x rows); C[ch][xm]
        int ch0 = blockIdx.x * 128, xm0 = blockIdx.y * 128;
        f32x4 acc[4][4] = {};
        for (int k0 = 0; k0 < K; k0 += 32) {
            __syncthreads();
#pragma unroll
            for (int ps = 0; ps < 2; ps++) {
                int row = ps * 64 + wave * 16;
                gll16(&vwt[(ch0 + row + grow) * K + k0 + gcol], &Ash[row][0]);
                gll16(&xhi[(xm0 + row + grow) * K + k0 + gcol], &Bsh[row][0]);
            }
            __syncthreads();
            bf16x8 af[4], bfr[4];
#pragma unroll
            for (int mi = 0; mi < 4; mi++)
                af[mi] = *(const bf16x8*)&Ash[wm + mi * 16 + l15][sA];
#pragma unroll
            for (int ni = 0; ni < 4; ni++)
                bfr[ni] = *(const bf16x8*)&Bsh[wn + ni * 16 + l15][sA];
#pragma unroll
            for (int mi = 0; mi < 4; mi++)
#pragma unroll
                for (int ni = 0; ni < 4; ni++)
                    acc[mi][ni] = __builtin_amdgcn_mfma_f32_16x16x32_bf16(
                        af[mi], bfr[ni], acc[mi][ni], 0, 0, 0);
        }
#pragma unroll
        for (int mi = 0; mi < 4; mi++)
#pragma unroll
            for (int ni = 0; ni < 4; ni++)
#pragma unroll
                for (int rg = 0; rg < 4; rg++) {
                    int ch = ch0 + wm + mi * 16 + quad * 4 + rg;
                    int xm = xm0 + wn + ni * 16 + l15;
                    int b = xm >> 11, s = xm & 2047;
                    int h = ch & 15,  d = ch >> 4;
                    Vt[((size_t)(b * NHEADS + h) * HDIM + d) * S_LEN + s] =
                        (__bf16)acc[mi][ni][rg];
                }
    }
}

// ---------------------------------------------------------------------------
// Output projection: out[m][n] = attnb[m][:] . owt[n][:], fp32 out.
// 64x128 tiles -> grid (8,64) = 512 blocks. Swizzled LDS.
// ---------------------------------------------------------------------------
__global__ __launch_bounds__(256) void out_gemm(const __bf16* __restrict__ A,
                                                const __bf16* __restrict__ Bt,
                                                float* __restrict__ out) {
    __shared__ __bf16 As[64][32];
    __shared__ __bf16 Bs[128][32];
    int tid  = threadIdx.x;
    int wave = tid >> 6, lane = tid & 63;
    int quad = lane >> 4, l15 = lane & 15;
    int m0 = blockIdx.y * 64, n0 = blockIdx.x * 128;
    int wm = (wave >> 1) * 32, wn = (wave & 1) * 64;
    int grow = lane >> 2;
    int gcol = (((lane & 3) - ((lane >> 3) & 3)) & 3) * 8;
    int sA   = ((quad + (l15 >> 1)) & 3) * 8;
    const int K = DMODEL;
    f32x4 acc[2][4] = {};

    for (int k0 = 0; k0 < K; k0 += 32) {
        __syncthreads();
        gll16(&A[(m0 + wave * 16 + grow) * K + k0 + gcol], &As[wave * 16][0]);
#pragma unroll
        for (int ps = 0; ps < 2; ps++) {
            int row = ps * 64 + wave * 16;
            gll16(&Bt[(n0 + row + grow) * K + k0 + gcol], &Bs[row][0]);
        }
        __syncthreads();
        bf16x8 af[2], bfr[4];
#pragma unroll
        for (int mi = 0; mi < 2; mi++)
            af[mi] = *(const bf16x8*)&As[wm + mi * 16 + l15][sA];
#pragma unroll
        for (int ni = 0; ni < 4; ni++)
            bfr[ni] = *(const bf16x8*)&Bs[wn + ni * 16 + l15][sA];
#pragma unroll
        for (int mi = 0; mi < 2; mi++)
#pragma unroll
            for (int ni = 0; ni < 4; ni++)
                acc[mi][ni] = __builtin_amdgcn_mfma_f32_16x16x32_bf16(
                    af[mi], bfr[ni], acc[mi][ni], 0, 0, 0);
    }

#pragma unroll
    for (int mi = 0; mi < 2; mi++)
#pragma unroll
        for (int ni = 0; ni < 4; ni++)
#pragma unroll
            for (int rg = 0; rg < 4; rg++) {
                int m = m0 + wm + mi * 16 + quad * 4 + rg;
                int n = n0 + wn + ni * 16 + l15;
                out[(size_t)m * DMODEL + n] = acc[mi][ni][rg];
            }
}

// ---------------------------------------------------------------------------
// Flash attention (v6, proven) — one block per 64-row q-tile. Grid 1024 =
// 4 blocks/CU; longest tiles dispatched first; 4 heads pinned per XCD.
// ---------------------------------------------------------------------------
__global__ __launch_bounds__(256, 4) void flash_attn(const __bf16* __restrict__ Qhi,
                                                     const __bf16* __restrict__ Qlo,
                                                     const __bf16* __restrict__ Khi,
                                                     const __bf16* __restrict__ Klo,
                                                     const __bf16* __restrict__ Vt,
                                                     __bf16* __restrict__ attn) {
    int id  = blockIdx.x;
    int xcd = id & 7, r = id >> 3;
    int bh  = xcd + 8 * (r & 3);           // 4 heads pinned per XCD
    int t   = 31 - (r >> 2);               // longest q-tiles dispatched first
    int b = bh >> 4, h = bh & 15;
    const __bf16* Qh_hi = Qhi + (size_t)b * S_LEN * DMODEL + h * HDIM;
    const __bf16* Qh_lo = Qlo + (size_t)b * S_LEN * DMODEL + h * HDIM;
    const __bf16* Kh_hi = Khi + (size_t)b * S_LEN * DMODEL + h * HDIM;
    const __bf16* Kh_lo = Klo + (size_t)b * S_LEN * DMODEL + h * HDIM;
    const __bf16* Vh    = Vt  + (size_t)bh * HDIM * S_LEN;

    int tid = threadIdx.x, wave = tid >> 6, lane = tid & 63;
    int quad = lane >> 4, l15 = lane & 15;
    int iters = t + 1;

    __shared__ __bf16 KhF[8 * 64 * 8];
    __shared__ __bf16 KlF[8 * 64 * 8];
    __shared__ __bf16 VF [8 * 64 * 8];
    __shared__ __bf16 Ps[4][16][72];

    int c1  = tid >> 6, key = tid & 63;
    int inner = (c1 * 16 + (key & 15)) * 8;
    int rK    = (key >> 4);
    int kdst0 = rK * 512 + inner, kdst1 = (4 + rK) * 512 + inner;
    const __bf16* vrow = Vh + (size_t)key * S_LEN;   // dim = key var

    int q0w = t * 64 + wave * 16;
    bf16x8 aqh0 = *(const bf16x8*)&Qh_hi[(size_t)(q0w + l15) * DMODEL + quad * 8];
    bf16x8 aqh1 = *(const bf16x8*)&Qh_hi[(size_t)(q0w + l15) * DMODEL + 32 + quad * 8];
    bf16x8 aql0 = *(const bf16x8*)&Qh_lo[(size_t)(q0w + l15) * DMODEL + quad * 8];
    bf16x8 aql1 = *(const bf16x8*)&Qh_lo[(size_t)(q0w + l15) * DMODEL + 32 + quad * 8];

    bf16x8 ones;
#pragma unroll
    for (int j = 0; j < 8; j++) ones[j] = (__bf16)1.0f;

    uint4 pk0, pk1, pl0, pl1, pv0, pv1;
    {   // prefetch tile kt=0
        const __bf16* sk = Kh_hi + (size_t)key * DMODEL;
        const __bf16* sl = Kh_lo + (size_t)key * DMODEL;
        pk0 = *(const uint4*)(sk + c1 * 8); pk1 = *(const uint4*)(sk + c1 * 8 + 32);
        pl0 = *(const uint4*)(sl + c1 * 8); pl1 = *(const uint4*)(sl + c1 * 8 + 32);
        pv0 = *(const uint4*)(vrow + c1 * 8); pv1 = *(const uint4*)(vrow + c1 * 8 + 32);
    }

    float m[4] = {-3e38f, -3e38f, -3e38f, -3e38f};
    f32x4 o[4] = {};
    f32x4 ol = {};
    int qrb = q0w + quad * 4;

    for (int i = 0; i < iters; i++) {
        int key0 = i * 64;
        bool diag = (i == iters - 1);

        __syncthreads();
        *(uint4*)&KhF[kdst0] = pk0;  *(uint4*)&KhF[kdst1] = pk1;
        *(uint4*)&KlF[kdst0] = pl0;  *(uint4*)&KlF[kdst1] = pl1;
        *(uint4*)&VF [kdst0] = pv0;  *(uint4*)&VF [kdst1] = pv1;
        __syncthreads();

        if (i + 1 < iters) {
            int key0n = (i + 1) * 64;
            const __bf16* sk = Kh_hi + (size_t)(key0n + key) * DMODEL;
            const __bf16* sl = Kh_lo + (size_t)(key0n + key) * DMODEL;
            pk0 = *(const uint4*)(sk + c1 * 8); pk1 = *(const uint4*)(sk + c1 * 8 + 32);
            pl0 = *(const uint4*)(sl + c1 * 8); pl1 = *(const uint4*)(sl + c1 * 8 + 32);
            pv0 = *(const uint4*)(vrow + key0n + c1 * 8);
            pv1 = *(const uint4*)(vrow + key0n + c1 * 8 + 32);
        }

        // ---- S(log2 domain) = Q K^T, split-bf16: hi.hi + hi.lo + lo.hi
        f32x4 sc[4] = {};
#pragma unroll
        for (int ni = 0; ni < 4; ni++) {
            bf16x8 kh0 = *(const bf16x8*)&KhF[(ni * 64 + lane) * 8];
            bf16x8 kh1 = *(const bf16x8*)&KhF[((4 + ni) * 64 + lane) * 8];
            bf16x8 kl0 = *(const bf16x8*)&KlF[(ni * 64 + lane) * 8];
            bf16x8 kl1 = *(const bf16x8*)&KlF[((4 + ni) * 64 + lane) * 8];
            sc[ni] = __builtin_amdgcn_mfma_f32_16x16x32_bf16(aqh0, kh0, sc[ni], 0, 0, 0);
            sc[ni] = __builtin_amdgcn_mfma_f32_16x16x32_bf16(aqh1, kh1, sc[ni], 0, 0, 0);
            sc[ni] = __builtin_amdgcn_mfma_f32_16x16x32_bf16(aqh0, kl0, sc[ni], 0, 0, 0);
            sc[ni] = __builtin_amdgcn_mfma_f32_16x16x32_bf16(aqh1, kl1, sc[ni], 0, 0, 0);
            sc[ni] = __builtin_amdgcn_mfma_f32_16x16x32_bf16(aql0, kh0, sc[ni], 0, 0, 0);
            sc[ni] = __builtin_amdgcn_mfma_f32_16x16x32_bf16(aql1, kh1, sc[ni], 0, 0, 0);
        }

        if (diag) {
#pragma unroll
            for (int ni = 0; ni < 4; ni++) {
                int keyi = key0 + ni * 16 + l15;
#pragma unroll
                for (int rg = 0; rg < 4; rg++)
                    if (keyi > qrb + rg) sc[ni][rg] = -1e30f;
            }
        }

#pragma unroll
        for (int rg = 0; rg < 4; rg++) {
            float mx = fmaxf(fmaxf(sc[0][rg], sc[1][rg]),
                             fmaxf(sc[2][rg], sc[3][rg]));
#pragma unroll
            for (int mm = 1; mm < 16; mm <<= 1)
                mx = fmaxf(mx, __shfl_xor(mx, mm, 64));
            float mnew  = fmaxf(m[rg], mx);
            float alpha = __builtin_amdgcn_exp2f(m[rg] - mnew);
            m[rg] = mnew;
#pragma unroll
            for (int ni = 0; ni < 4; ni++) {
                float px = __builtin_amdgcn_exp2f(sc[ni][rg] - mnew);
                Ps[wave][quad * 4 + rg][ni * 16 + l15] = (__bf16)px;
            }
            ol[rg] *= alpha;
#pragma unroll
            for (int ni = 0; ni < 4; ni++)
                o[ni][rg] *= alpha;
        }

#pragma unroll
        for (int step = 0; step < 2; step++) {
            bf16x8 ap = *(const bf16x8*)&Ps[wave][l15][step * 32 + quad * 8];
            ol = __builtin_amdgcn_mfma_f32_16x16x32_bf16(ap, ones, ol, 0, 0, 0);
#pragma unroll
            for (int ni = 0; ni < 4; ni++) {
                bf16x8 bv = *(const bf16x8*)&VF[((step * 4 + ni) * 64 + lane) * 8];
                o[ni] = __builtin_amdgcn_mfma_f32_16x16x32_bf16(ap, bv, o[ni], 0, 0, 0);
            }
        }
    }

    // ---- epilogue: coalesced merged-layout store
#pragma unroll
    for (int rg = 0; rg < 4; rg++) {
        float inv = 1.0f / ol[rg];
        int q = q0w + quad * 4 + rg;
#pragma unroll
        for (int ni = 0; ni < 4; ni++) {
            attn[((size_t)b * S_LEN + q) * DMODEL + h * HDIM + ni * 16 + l15] =
                (__bf16)(o[ni][rg] * inv);
        }
    }
}

// ---------------------------------------------------------------------------
extern "C" void kernel_launch(void* const* d_in, const int* in_sizes, int n_in,
                              void* d_out, int out_size, void* d_ws, size_t ws_size,
                              hipStream_t stream) {
    const float* x  = (const float*)d_in[0];
    const float* qw = (const float*)d_in[1];
    const float* kw = (const float*)d_in[2];
    const float* vw = (const float*)d_in[3];
    const float* ow = (const float*)d_in[4];

    char* ws = (char*)d_ws;
    const size_t MB = 1024 * 1024;
    __bf16* xhi   = (__bf16*)(ws);             //  8 MB  [4096,1024]
    __bf16* xlo   = (__bf16*)(ws + 8 * MB);    //  8 MB  (reused as attnb later)
    __bf16* qwthi = (__bf16*)(ws + 16 * MB);   //  2 MB each
    __bf16* qwtlo = (__bf16*)(ws + 18 * MB);
    __bf16* kwthi = (__bf16*)(ws + 20 * MB);
    __bf16* kwtlo = (__bf16*)(ws + 22 * MB);
    __bf16* vwt   = (__bf16*)(ws + 24 * MB);
    __bf16* owt   = (__bf16*)(ws + 26 * MB);
    __bf16* Qhi_b = (__bf16*)(ws + 28 * MB);   //  8 MB  merged [B*S][D]
    __bf16* Qlo_b = (__bf16*)(ws + 36 * MB);
    __bf16* Khi_b = (__bf16*)(ws + 44 * MB);
    __bf16* Klo_b = (__bf16*)(ws + 52 * MB);
    __bf16* Vtb   = (__bf16*)(ws + 60 * MB);   //  8 MB  [B,H,64,S]
    __bf16* attnb = xlo;                       //  alias: xlo dead after QKV GEMMs

    prep_all<<<8192, 256, 0, stream>>>(x, qw, kw, vw, ow,
                                       xhi, xlo, qwthi, qwtlo, kwthi, kwtlo,
                                       vwt, owt);

    qkv_gemm<<<dim3(8, 32, 3), 256, 0, stream>>>(
        xhi, xlo, qwthi, qwtlo, kwthi, kwtlo, vwt,
        Qhi_b, Qlo_b, Khi_b, Klo_b, Vtb);

    flash_attn<<<1024, 256, 0, stream>>>(Qhi_b, Qlo_b, Khi_b, Klo_b, Vtb, attnb);

    out_gemm<<<dim3(8, 64), 256, 0, stream>>>(attnb, owt, (float*)d_out);
}